// Round 17
// baseline (376.077 us; speedup 1.0000x reference)
//
#include <hip/hip_runtime.h>

// DCAttention: B=2, L=2048, D=1024, H=16, DK=64. Runtime dtype detect; compute bf16.
// Proj half-fold: Q = conv3(q_in_pad) @ H^T + bvec, H_k = Wp2@Cw_k (+Wp1 mid tap).
// attn v9: split-kv x2, KVBLK=32, 20KB LDS -> 8 blocks/CU; linear partial combine.
typedef __bf16 bf16_t;
typedef __bf16 bf16x8 __attribute__((ext_vector_type(8)));
typedef __bf16 bf16x4 __attribute__((ext_vector_type(4)));
typedef float f32x4 __attribute__((ext_vector_type(4)));
typedef unsigned uint2v __attribute__((ext_vector_type(2)));

__device__ __forceinline__ void gload_lds16(const bf16_t* g, bf16_t* l) {
  __builtin_amdgcn_global_load_lds(
      (__attribute__((address_space(1))) void*)g,
      (__attribute__((address_space(3))) void*)l, 16, 0, 0);
}

// ---- dtype detection ----
__global__ void k_detect(const unsigned int* __restrict__ xw, int* __restrict__ flag) {
  __shared__ int red[256];
  int c = 0;
  for (int j = 0; j < 16; ++j) {
    unsigned int w = xw[threadIdx.x + (j << 8)];
    unsigned int e = (w >> 7) & 0xFF;
    c += (e >= 100 && e <= 150) ? 1 : 0;
  }
  red[threadIdx.x] = c;
  __syncthreads();
  for (int s = 128; s > 0; s >>= 1) {
    if (threadIdx.x < s) red[threadIdx.x] += red[threadIdx.x + s];
    __syncthreads();
  }
  if (threadIdx.x == 0) flag[0] = (red[0] > 2048) ? 1 : 0;  // 1 = bf16, 0 = f32
}

// ---- canonicalize inputs to bf16 ----
__device__ __constant__ long c_offs[26] = {
    0, 4194304, 4195328, 4196352, 4197376, 4198400, 4199424, 6296576,
    6297600, 8394752, 8395776, 8401920, 8403968, 8436736, 8436752,
    8442896, 8444944, 8477712, 8477728,
    0, 1048576, 2097152, 3145728,
    0, 1048576, 1049600};
struct CanonArgs { const void* src[18]; };

__global__ void k_canon(CanonArgs a, int base, int n, const int* __restrict__ flag,
                        bf16_t* __restrict__ dst) {
  long e0 = ((long)blockIdx.x * 256 + threadIdx.x) * 8;
  if (e0 >= c_offs[base + n]) return;
  int k = 0;
  while (e0 >= c_offs[base + k + 1]) ++k;
  const long rel = e0 - c_offs[base + k];
  if (flag[0]) {
    *(bf16x8*)&dst[e0] = *(const bf16x8*)((const bf16_t*)a.src[k] + rel);
  } else {
    const float* sf = (const float*)a.src[k] + rel;
    f32x4 lo = *(const f32x4*)sf;
    f32x4 hi = *(const f32x4*)(sf + 4);
    bf16x8 o;
    o[0] = (bf16_t)lo[0]; o[1] = (bf16_t)lo[1]; o[2] = (bf16_t)lo[2]; o[3] = (bf16_t)lo[3];
    o[4] = (bf16_t)hi[0]; o[5] = (bf16_t)hi[1]; o[6] = (bf16_t)hi[2]; o[7] = (bf16_t)hi[3];
    *(bf16x8*)&dst[e0] = o;
  }
}

// zero rows 0 and 2049 of each of the 4 pad batches; zero zvec
__global__ void k_zero_pads(bf16_t* __restrict__ pad, bf16_t* __restrict__ zvec) {
  int idx = blockIdx.x * 256 + threadIdx.x;
  if (idx < 1024) zvec[idx] = (bf16_t)0.0f;
  if (idx >= 8192) return;
  int b = idx >> 11;
  int r = (idx >> 10) & 1;
  int c = idx & 1023;
  long row = (long)b * 2050 + (r ? 2049 : 0);
  pad[row * 1024 + c] = (bf16_t)0.0f;
}

// conv weight (O=o, I=i, 3=k) -> ctT[(k*1024+i), o]  (tiled LDS transpose)
__global__ __launch_bounds__(256) void k_ctT(
    const void* __restrict__ wq, const void* __restrict__ wk,
    bf16_t* __restrict__ dq, bf16_t* __restrict__ dk,
    const int* __restrict__ flag) {
  __shared__ bf16_t T[64][72];
  int blk = blockIdx.x;
  const int br = blk >= 768;
  if (br) blk -= 768;
  const void* w = br ? wk : wq;
  bf16_t* dst = br ? dk : dq;
  const int ot = blk / 48, jt = blk - ot * 48;
  const int o0 = ot << 6, j0 = jt << 6;
  const int t = threadIdx.x;
  const int f = flag[0];
#pragma unroll
  for (int it = 0; it < 2; ++it) {
    const int ch = t + (it << 8);
    const int r = ch >> 3, c8 = (ch & 7) << 3;
    const long off = (long)(o0 + r) * 3072 + j0 + c8;
    if (f) {
      *(bf16x8*)&T[r][c8] = *(const bf16x8*)((const bf16_t*)w + off);
    } else {
      const float* sf = (const float*)w + off;
      bf16x8 o8;
#pragma unroll
      for (int e = 0; e < 8; ++e) o8[e] = (bf16_t)sf[e];
      *(bf16x8*)&T[r][c8] = o8;
    }
  }
  __syncthreads();
  const int j = t >> 2, oc0 = (t & 3) << 4;
  const int jj = j0 + j;
  const int drow = (jj % 3) * 1024 + jj / 3;   // tap*1024 + i
  bf16_t* dp = dst + (long)drow * 1024 + o0 + oc0;
#pragma unroll
  for (int s = 0; s < 16; ++s) dp[s] = T[oc0 + s][j];
}

// fused: blocks [0,1024) H middle tap += Wp1; blocks [1024,1032) bvec
__global__ __launch_bounds__(256) void k_prep2(
    bf16_t* __restrict__ Hq, bf16_t* __restrict__ Hk,
    const bf16_t* __restrict__ qp, const bf16_t* __restrict__ kp,
    const bf16_t* __restrict__ cqb, const bf16_t* __restrict__ ckb,
    const bf16_t* __restrict__ qpb, const bf16_t* __restrict__ kpb,
    bf16_t* __restrict__ bvec) {
  if (blockIdx.x < 1024) {
    const long e0 = ((long)blockIdx.x * 256 + threadIdx.x) * 8;
    if (e0 >= 2097152L) return;
    const int br = (int)(e0 >> 20);
    const int rem = (int)(e0 & 1048575);
    const int o = rem >> 10, i = rem & 1023;
    bf16_t* hh = (br ? Hk : Hq) + (long)o * 3072 + 1024 + i;
    const bf16_t* ww = (br ? kp : qp) + (long)o * 2048 + i;
    bf16x8 a = *(const bf16x8*)hh;
    bf16x8 b2 = *(const bf16x8*)ww;
    bf16x8 r;
#pragma unroll
    for (int e = 0; e < 8; ++e) r[e] = (bf16_t)((float)a[e] + (float)b2[e]);
    *(bf16x8*)hh = r;
  } else {
    const int idx = (blockIdx.x - 1024) * 256 + threadIdx.x;
    if (idx >= 2048) return;
    const int br = idx >> 10, o = idx & 1023;
    const bf16_t* wrow = (br ? kp : qp) + (long)o * 2048 + 1024;
    const bf16_t* cb = br ? ckb : cqb;
    float s = 0.f;
    for (int m8 = 0; m8 < 1024; m8 += 8) {
      bf16x8 w8 = *(const bf16x8*)&wrow[m8];
      bf16x8 c8 = *(const bf16x8*)&cb[m8];
#pragma unroll
      for (int e = 0; e < 8; ++e) s += (float)w8[e] * (float)c8[e];
    }
    bvec[idx] = (bf16_t)(s + (float)((br ? kpb : qpb)[o]));
  }
}

// ---- generalized 128xBN GEMM: C = A*B^T + bias, two-level (batch,tap) jumps ----
// LDS tiles XOR-chunk-swizzled (T2); single-barrier counted pipeline; BK templated.
struct GemmP {
  const bf16_t *A0;
  const bf16_t *B0, *B1, *B2;
  const bf16_t *bias0, *bias1, *bias2;
  bf16_t *C0, *C1, *C2;
  long a_jump, at_jump;
  long cj0, cj1, cj2, ct_jump;
  long b_jump;            // if nonzero: Bp = B0 + bidx*b_jump
  int rpb, rpt, lda, ldb, bsel_by_n, bshift, K, csel_by_n;
  int crs0, ccs0, crs1, ccs1, crs2, ccs2;
};

template <int BN, int BK, bool FINAL>
__global__ __launch_bounds__(256) void k_gemm(GemmP p, const int* __restrict__ flagp) {
  __shared__ __align__(16) bf16_t As[2][128 * BK];
  __shared__ __align__(16) bf16_t Bs[2][BN * BK];
  constexpr int CPR = BK / 8;        // 16B chunks per row
  const int tid = threadIdx.x;
  const int gx = gridDim.x;
  int lin = blockIdx.y * gx + blockIdx.x;
  const int nwg = gx * gridDim.y;
  lin = ((lin & 7) * (nwg >> 3)) + (lin >> 3);   // XCD-bijective swizzle (nwg % 8 == 0)
  const int n0 = (lin % gx) * BN;
  const int m0 = (lin / gx) << 7;
  const int batch = m0 / p.rpb;
  const int tap = (m0 - batch * p.rpb) / p.rpt;
  const int bidx = p.bsel_by_n ? (n0 >> 10) : (m0 >> p.bshift);
  const bf16_t* Bp = p.b_jump ? (p.B0 + (long)bidx * p.b_jump)
                              : (bidx == 0 ? p.B0 : (bidx == 1 ? p.B1 : p.B2));
  const bf16_t* biasp = bidx == 0 ? p.bias0 : (bidx == 1 ? p.bias1 : p.bias2);
  const long abase = (long)batch * p.a_jump + (long)tap * p.at_jump;
  const int wid = tid >> 6, lane = tid & 63;
  const int l15 = lane & 15, lg = lane >> 4;
  const int nloc = n0 & 1023;

  constexpr int MI = (BN == 128) ? 4 : 2;
  const int wr = (BN == 128) ? ((wid >> 1) << 6) : (wid << 5);
  const int wc = (BN == 128) ? ((wid & 1) << 6) : 0;
  const int l15sw = (l15 >> 1) & (CPR - 1);

  f32x4 acc[MI][4];
#pragma unroll
  for (int i = 0; i < MI; ++i)
#pragma unroll
    for (int j = 0; j < 4; ++j) acc[i][j] = (f32x4){0.f, 0.f, 0.f, 0.f};

  auto stage = [&](int bufi, int k) {
#pragma unroll
    for (int it = 0; it < (128 * CPR) / 256; ++it) {   // A tile chunks
      const int c = it * 256 + tid;
      const int row = c / CPR, kc = c % CPR;
      const int kg = k + ((kc ^ ((row >> 1) & (CPR - 1))) << 3);
      gload_lds16(p.A0 + abase + (long)(m0 + row) * p.lda + kg, &As[bufi][c << 3]);
    }
#pragma unroll
    for (int it = 0; it < (BN * CPR) / 256; ++it) {    // B tile chunks
      const int c = it * 256 + tid;
      const int row = c / CPR, kc = c % CPR;
      const int kg = k + ((kc ^ ((row >> 1) & (CPR - 1))) << 3);
      gload_lds16(Bp + (long)(nloc + row) * p.ldb + kg, &Bs[bufi][c << 3]);
    }
  };

  const int nk = p.K / BK;
  int buf = 0;
  stage(0, 0);
  asm volatile("s_waitcnt vmcnt(0)" ::: "memory");
  __builtin_amdgcn_s_barrier();
  __builtin_amdgcn_sched_barrier(0);
  for (int kt = 0; kt < nk; ++kt) {
    if (kt + 1 < nk) stage(buf ^ 1, (kt + 1) * BK);
#pragma unroll
    for (int kh = 0; kh < BK / 32; ++kh) {
      bf16x8 af[MI], bfr[4];
      const int csw = (((kh << 2) | lg) ^ l15sw) << 3;
#pragma unroll
      for (int i = 0; i < MI; ++i)
        af[i] = *(const bf16x8*)&As[buf][(wr + (i << 4) + l15) * BK + csw];
#pragma unroll
      for (int j = 0; j < 4; ++j)
        bfr[j] = *(const bf16x8*)&Bs[buf][(wc + (j << 4) + l15) * BK + csw];
#pragma unroll
      for (int i = 0; i < MI; ++i)
#pragma unroll
        for (int j = 0; j < 4; ++j)
          acc[i][j] = __builtin_amdgcn_mfma_f32_16x16x32_bf16(af[i], bfr[j], acc[i][j], 0, 0, 0);
    }
    if (kt + 1 < nk) asm volatile("s_waitcnt vmcnt(0)" ::: "memory");
    __builtin_amdgcn_s_barrier();
    __builtin_amdgcn_sched_barrier(0);
    buf ^= 1;
  }

  const int cp = p.csel_by_n ? (n0 >> 10) : (m0 >> p.bshift);
  bf16_t* Cb = cp == 0 ? p.C0 : (cp == 1 ? p.C1 : p.C2);
  const int crs = cp == 0 ? p.crs0 : (cp == 1 ? p.crs1 : p.crs2);
  const int ccs = cp == 0 ? p.ccs0 : (cp == 1 ? p.ccs1 : p.ccs2);
  const long cj = cp == 0 ? p.cj0 : (cp == 1 ? p.cj1 : p.cj2);
  const bool f32out = FINAL && (flagp[0] == 0);
  const long cbase = (long)batch * cj + (long)tap * p.ct_jump;
#pragma unroll
  for (int i = 0; i < MI; ++i) {
    const int row = m0 + wr + (i << 4) + (lg << 2);
#pragma unroll
    for (int j = 0; j < 4; ++j) {
      const int col = nloc + wc + (j << 4) + l15;
      const float bv = (float)biasp[col];
#pragma unroll
      for (int r = 0; r < 4; ++r) {
        const float val = acc[i][j][r] + bv;
        const long ci = cbase + (long)(row + r) * crs + (long)col * ccs;
        if (FINAL && f32out) ((float*)Cb)[ci] = val;
        else Cb[ci] = (bf16_t)val;
      }
    }
  }
}

// tau/delta: depthwise conv3 -> gelu(erf) -> pointwise (2D->H) -> sigmoid.
// dlt is pre-multiplied by log2(e) for the exp2-domain softmax.
__global__ __launch_bounds__(256) void k_taudelta(
    const bf16_t* __restrict__ x,
    const bf16_t* __restrict__ t1w, const bf16_t* __restrict__ t1b,
    const bf16_t* __restrict__ t2w, const bf16_t* __restrict__ t2b,
    const bf16_t* __restrict__ d1w, const bf16_t* __restrict__ d1b,
    const bf16_t* __restrict__ d2w, const bf16_t* __restrict__ d2b,
    float* __restrict__ tau, float* __restrict__ dlt)
{
  const int bt = blockIdx.x;
  const int t = bt & 2047;
  const int b = bt >> 11;
  const int tid = threadIdx.x;
  const bf16_t* xr = x + ((long)bt << 10);

  float acc[32];
#pragma unroll
  for (int i = 0; i < 32; ++i) acc[i] = 0.f;

  for (int j = 0; j < 8; ++j) {
    const int c = tid + (j << 8);
    const int src = c >> 1;
    const float x0 = (float)xr[src];
    const float xm = (t > 0) ? (float)xr[src - 1024] : 0.f;
    const float xp = (t < 2047) ? (float)xr[src + 1024] : 0.f;
    float st = (float)t1w[3 * c] * xm + (float)t1w[3 * c + 1] * x0 +
               (float)t1w[3 * c + 2] * xp + (float)t1b[c];
    float sd = (float)d1w[3 * c] * xm + (float)d1w[3 * c + 1] * x0 +
               (float)d1w[3 * c + 2] * xp + (float)d1b[c];
    const float gt = 0.5f * st * (1.f + erff(st * 0.70710678118f));
    const float gd = 0.5f * sd * (1.f + erff(sd * 0.70710678118f));
#pragma unroll
    for (int h = 0; h < 16; ++h) {
      acc[h]      += (float)t2w[(h << 11) + c] * gt;
      acc[16 + h] += (float)d2w[(h << 11) + c] * gd;
    }
  }

  __shared__ float red[256][33];
  __shared__ float red2[8][32];
#pragma unroll
  for (int i = 0; i < 32; ++i) red[tid][i] = acc[i];
  __syncthreads();
  const int i = tid & 31, g = tid >> 5;
  float p = 0.f;
#pragma unroll
  for (int k2 = 0; k2 < 32; ++k2) p += red[(g << 5) + k2][i];
  __syncthreads();
  red2[g][i] = p;
  __syncthreads();
  if (tid < 32) {
    float s = 0.f;
#pragma unroll
    for (int g2 = 0; g2 < 8; ++g2) s += red2[g2][tid];
    const int h = tid & 15;
    if (tid < 16) {
      s += (float)t2b[h];
      tau[((long)((b << 4) + h) << 11) + t] = 1.f / (1.f + __expf(-s));
    } else {
      s += (float)d2b[h];
      dlt[((long)((b << 4) + h) << 11) + t] =
          1.4426950408889634f / (1.f + __expf(-s));
    }
  }
}

__device__ __forceinline__ unsigned pk2(float a, float b) {
  union { bf16_t h[2]; unsigned u; } z;
  z.h[0] = (bf16_t)a; z.h[1] = (bf16_t)b;
  return z.u;
}

// Flash attention v9: split-kv x2 (linear combine; no-max softmax makes partials
// additive), KVBLK=32, 20KB LDS -> 8 blocks/CU. exp2-domain, ones-MFMA row sum,
// double-buffered K/V, single-barrier pipeline. Writes bf16 O-partials + f32 L.
__global__ __launch_bounds__(256, 8) void k_attn(
    const bf16_t* __restrict__ QKb, const bf16_t* __restrict__ VT,
    const float* __restrict__ tau, const float* __restrict__ dlt,
    bf16_t* __restrict__ pO, float* __restrict__ Lp)
{
  const int lin = blockIdx.x;
  const int wg = ((lin & 7) << 8) + (lin >> 3);   // 2048 blocks, XCD-chunked
  const int bh = wg >> 6;
  const int s = (wg >> 5) & 1;
  const int qt = wg & 31;
  const int tid = threadIdx.x;
  const int lane = tid & 63;
  const int wid = tid >> 6;
  const int l15 = lane & 15, lg = lane >> 4;
  const int b = bh >> 4, h = bh & 15;
  const int qbase = (qt << 6) + (wid << 4);
  const int kv0 = s << 10;

  const bf16_t* Qp = QKb + ((long)b << 21) + (h << 6);
  const bf16_t* Kp = QKb + 4194304 + ((long)b << 21) + (h << 6) + ((long)kv0 << 10);
  const bf16_t* Vp = VT + ((long)bh << 17) + kv0;

  __shared__ __align__(16) bf16_t Ks[2][2048];   // 32 kv x 64 d
  __shared__ __align__(16) bf16_t Vs[2][2048];   // 64 d  x 32 kv
  __shared__ unsigned Plds[4][16][16];           // 4 KB

  bf16x8 qf[2];
#pragma unroll
  for (int kd = 0; kd < 2; ++kd)
    qf[kd] = *(const bf16x8*)&Qp[((long)(qbase + l15) << 10) + (kd << 5) + (lg << 3)];
  const float tq = tau[((long)bh << 11) + qbase + l15] * (0.125f * 1.4426950408889634f);

  bf16x8 onesf;
#pragma unroll
  for (int e = 0; e < 8; ++e) onesf[e] = (bf16_t)1.0f;

  f32x4 accO[4];
#pragma unroll
  for (int d = 0; d < 4; ++d) accO[d] = (f32x4){0.f, 0.f, 0.f, 0.f};
  f32x4 accL = (f32x4){0.f, 0.f, 0.f, 0.f};

  // K fragment slots (row stride 128B): data slot ^ (row&7), row%16 = l15
  const int c0 = ((lg ^ (l15 & 7)) << 3);
  const int c1 = (((4 | lg) ^ (l15 & 7)) << 3);
  // V fragment slot (row stride 64B): data slot lg ^ ((row>>1)&3)
  const int vsl = ((lg ^ ((l15 >> 1) & 3)) << 3);
  const int xr4 = ((l15 >> 1) & 3) << 2;
  // staging: K thread t -> row t>>3, chunk (t&7)^(row&7); V row t>>2, chunk (t&3)^((row>>1)&3)
  const int kr = tid >> 3, kc = ((tid & 7) ^ (kr & 7)) << 3;
  const int vr = tid >> 2, vc = (((tid & 3) ^ ((vr >> 1) & 3)) << 3);
  const bf16_t* kb0 = Kp + ((long)kr << 10) + kc;
  const bf16_t* vb0 = Vp + ((long)vr << 11) + vc;
  const float* dlp = dlt + ((long)bh << 11) + kv0 + (lg << 2);

  auto stageKV = [&](int bufi, int kk) {
    gload_lds16(kb0 + ((long)kk << 10), &Ks[bufi][tid << 3]);
    gload_lds16(vb0 + kk, &Vs[bufi][tid << 3]);
  };

  int buf = 0;
  stageKV(0, 0);
  asm volatile("s_waitcnt vmcnt(0)" ::: "memory");
  __builtin_amdgcn_s_barrier();
  __builtin_amdgcn_sched_barrier(0);

  for (int kk = 0; kk < 1024; kk += 32) {
    if (kk + 32 < 1024) stageKV(buf ^ 1, kk + 32);

    f32x4 st[2];
    __builtin_amdgcn_s_setprio(1);
#pragma unroll
    for (int kb = 0; kb < 2; ++kb) {
      const int rk = ((kb << 4) + l15) << 6;
      f32x4 z = (f32x4){0.f, 0.f, 0.f, 0.f};
      z = __builtin_amdgcn_mfma_f32_16x16x32_bf16(
          *(const bf16x8*)&Ks[buf][rk + c0], qf[0], z, 0, 0, 0);
      z = __builtin_amdgcn_mfma_f32_16x16x32_bf16(
          *(const bf16x8*)&Ks[buf][rk + c1], qf[1], z, 0, 0, 0);
      st[kb] = z;
    }
    __builtin_amdgcn_s_setprio(0);

#pragma unroll
    for (int kb = 0; kb < 2; ++kb) {
      const f32x4 dl = *(const f32x4*)(dlp + kk + (kb << 4));
      const float p0 = exp2f(fmaf(st[kb][0], tq, dl[0]));
      const float p1 = exp2f(fmaf(st[kb][1], tq, dl[1]));
      const float p2 = exp2f(fmaf(st[kb][2], tq, dl[2]));
      const float p3 = exp2f(fmaf(st[kb][3], tq, dl[3]));
      uint2v pp;
      pp[0] = pk2(p0, p1);
      pp[1] = pk2(p2, p3);
      *(uint2v*)&Plds[wid][l15][((kb << 3) + (lg << 1)) ^ xr4] = pp;
    }
    asm volatile("s_waitcnt lgkmcnt(0)" ::: "memory");
    __builtin_amdgcn_sched_barrier(0);
    const bf16x8 pf0 = *(const bf16x8*)&Plds[wid][l15][(lg << 2) ^ xr4];
    asm volatile("s_waitcnt lgkmcnt(0)" ::: "memory");
    __builtin_amdgcn_sched_barrier(0);

    __builtin_amdgcn_s_setprio(1);
#pragma unroll
    for (int d = 0; d < 4; ++d) {
      const int rv = ((d << 4) + l15) << 5;
      accO[d] = __builtin_amdgcn_mfma_f32_16x16x32_bf16(
          *(const bf16x8*)&Vs[buf][rv + vsl], pf0, accO[d], 0, 0, 0);
    }
    accL = __builtin_amdgcn_mfma_f32_16x16x32_bf16(onesf, pf0, accL, 0, 0, 0);
    __builtin_amdgcn_s_setprio(0);

    if (kk + 32 < 1024) asm volatile("s_waitcnt vmcnt(0)" ::: "memory");
    __builtin_amdgcn_s_barrier();
    __builtin_amdgcn_sched_barrier(0);
    buf ^= 1;
  }

  // partial store: pO[s][(bh*2048+q)*64 + d], Lp[s][bh*2048+q]
  bf16_t* pOb = pO + (long)s * 4194304 + (((long)(bh << 11) + qbase + l15) << 6);
#pragma unroll
  for (int d = 0; d < 4; ++d) {
    bf16x4 ov;
#pragma unroll
    for (int r = 0; r < 4; ++r) ov[r] = (bf16_t)accO[d][r];
    *(bf16x4*)&pOb[(d << 4) + (lg << 2)] = ov;
  }
  if (lg == 0) Lp[s * 65536 + (bh << 11) + qbase + l15] = accL[0];
}

// combine: out[(b*2048+q)*1024 + h*64 + d] = (pO0+pO1) / (L0+L1)
__global__ __launch_bounds__(256) void k_comb(
    const bf16_t* __restrict__ pO, const float* __restrict__ Lp,
    bf16_t* __restrict__ O) {
  const long e0 = ((long)blockIdx.x * 256 + threadIdx.x) * 8;
  if (e0 >= 4194304L) return;
  const int bh = (int)(e0 >> 17);
  const int rem = (int)(e0 & 131071);
  const int q = rem >> 6, d0 = rem & 63;
  const bf16x8 o0 = *(const bf16x8*)&pO[e0];
  const bf16x8 o1 = *(const bf16x8*)&pO[4194304 + e0];
  const int qi = (bh << 11) + q;
  const float inv = 1.f / (Lp[qi] + Lp[65536 + qi]);
  bf16x8 ov;
#pragma unroll
  for (int e = 0; e < 8; ++e)
    ov[e] = (bf16_t)(((float)o0[e] + (float)o1[e]) * inv);
  const int b = bh >> 4, h = bh & 15;
  *(bf16x8*)&O[(((long)(b << 11) + q) << 10) + (h << 6) + d0] = ov;
}

extern "C" void kernel_launch(void* const* d_in, const int* in_sizes, int n_in,
                              void* d_out, int out_size, void* d_ws, size_t ws_size,
                              hipStream_t stream) {
  char* w = (char*)d_ws;
  int* flag     = (int*)w;                      // 16 B
  bf16_t* canon = (bf16_t*)(w + 16);            // 16,955,456 B
  bf16_t* pad   = (bf16_t*)(w + 16955472);      // 16,793,600 B (4 batches x 2050 x 1024)
  bf16_t* swq   = (bf16_t*)(w + 33749072);      // 6,291,456 B (Wq/Wk/Wv; later tau/dlt/bvec/zvec/Lp)
  bf16_t* cvout = (bf16_t*)(w + 40040528);      // 8,388,608 B (H_q; later out weights)
  bf16_t* QKb   = (bf16_t*)(w + 48429136);      // 16,777,216 B (ctT -> Q|K)
  bf16_t* VT    = (bf16_t*)(w + 65206352);      // 8,388,608 B

  // canon element offsets
  bf16_t* xc      = canon;
  bf16_t* Wq_b    = canon + 4194304;
  bf16_t* Wk_b    = canon + 4195328;
  bf16_t* Wv_b    = canon + 4196352;
  bf16_t* convq_b = canon + 4197376;
  bf16_t* convk_b = canon + 4198400;
  bf16_t* qproj_w = canon + 4199424;
  bf16_t* qproj_b = canon + 6296576;
  bf16_t* kproj_w = canon + 6297600;
  bf16_t* kproj_b = canon + 8394752;
  bf16_t* tau1_w  = canon + 8395776;
  bf16_t* tau1_b  = canon + 8401920;
  bf16_t* tau2_w  = canon + 8403968;
  bf16_t* tau2_b  = canon + 8436736;
  bf16_t* del1_w  = canon + 8436752;
  bf16_t* del1_b  = canon + 8442896;
  bf16_t* del2_w  = canon + 8444944;
  bf16_t* del2_b  = canon + 8477712;

  bf16_t* pad_q = pad;
  bf16_t* Wq_w = swq, *Wk_w = swq + 1048576, *Wv_w = swq + 2097152;
  float* tau = (float*)swq;                     // after QKV GEMM, swq is dead
  float* dlt = (float*)((char*)swq + 262144);
  bf16_t* bvec = (bf16_t*)((char*)swq + 524288);
  bf16_t* zvec = (bf16_t*)((char*)swq + 528384);
  float* Lp   = (float*)((char*)swq + 540672);  // 524,288 B (2 x 65536 f32)
  bf16_t* ctT_q = QKb;                          // 3072x1024 per branch
  bf16_t* ctT_k = QKb + 3145728;
  bf16_t* Hq = cvout;                           // [o][tap*1024+i]
  bf16_t* Hk = xc;                              // x dead after QKV + taudelta
  const long hk_delta = (long)(Hk - Hq);
  bf16_t* pO = pad;                             // pad dead after main GEMM (16.78 MB)
  bf16_t* outw_bf = cvout;                      // Hq dead after main GEMM
  bf16_t* outb_bf = cvout + 1048576;
  bf16_t* attn_out = xc;                        // Hk dead after main GEMM

  k_detect<<<1, 256, 0, stream>>>((const unsigned int*)d_in[0], flag);

  CanonArgs ca{};
  {
    const int idxA[18] = {0, 2, 4, 6, 8, 10, 11, 12, 13, 14,
                          15, 16, 17, 18, 19, 20, 21, 22};
    for (int i = 0; i < 18; ++i) ca.src[i] = d_in[idxA[i]];
    k_canon<<<4140, 256, 0, stream>>>(ca, 0, 18, flag, canon);
  }
  {
    CanonArgs cw{};
    cw.src[0] = d_in[1]; cw.src[1] = d_in[3]; cw.src[2] = d_in[5];
    k_canon<<<1536, 256, 0, stream>>>(cw, 19, 3, flag, swq);
  }
  k_zero_pads<<<32, 256, 0, stream>>>(pad, zvec);

  // ---- fused QKV in-projection: M=4096, N=3072, K=1024 (BK=32, 3 blocks/CU) ----
  {
    GemmP p{};
    p.A0 = xc;
    p.B0 = Wq_w; p.B1 = Wk_w; p.B2 = Wv_w;
    p.bias0 = Wq_b; p.bias1 = Wk_b; p.bias2 = Wv_b;
    p.C0 = pad_q + 1024; p.C1 = pad_q + 4198400 + 1024; p.C2 = VT;
    p.a_jump = 0; p.at_jump = 0;
    p.cj0 = 2048; p.cj1 = 2048; p.cj2 = 2095104; p.ct_jump = 0;
    p.b_jump = 0;
    p.rpb = 2048; p.rpt = 1 << 30; p.lda = 1024; p.ldb = 1024;
    p.bsel_by_n = 1; p.bshift = 12; p.K = 1024; p.csel_by_n = 1;
    p.crs0 = 1024; p.ccs0 = 1; p.crs1 = 1024; p.ccs1 = 1; p.crs2 = 1; p.ccs2 = 2048;
    k_gemm<128, 32, false><<<dim3(24, 32), 256, 0, stream>>>(p, flag);
  }

  // tau/delta (into dead swq region)
  k_taudelta<<<4096, 256, 0, stream>>>(xc, tau1_w, tau1_b, tau2_w, tau2_b,
                                       del1_w, del1_b, del2_w, del2_b, tau, dlt);

  // conv weight transposes ctT[(k,i), o]
  k_ctT<<<1536, 256, 0, stream>>>(d_in[7], d_in[9], ctT_q, ctT_k, flag);

  // ---- H = Wp2 @ Cw: M=6144 ((br,tap,o)), N=1024 (i), K=1024 (BK=64) ----
  {
    GemmP p{};
    p.A0 = qproj_w + 1024;
    p.B0 = ctT_q; p.B1 = ctT_q; p.B2 = ctT_q;
    p.bias0 = p.bias1 = p.bias2 = zvec;
    p.C0 = p.C1 = p.C2 = Hq;
    p.a_jump = (long)(kproj_w - qproj_w) - 3072L * 2048;   // -4193280
    p.at_jump = -2097152;
    p.cj0 = p.cj1 = p.cj2 = hk_delta - 9437184;
    p.ct_jump = -3144704;
    p.b_jump = 1048576;
    p.rpb = 3072; p.rpt = 1024; p.lda = 2048; p.ldb = 1024;
    p.bsel_by_n = 0; p.bshift = 10; p.K = 1024; p.csel_by_n = 0;
    p.crs0 = p.crs1 = p.crs2 = 3072; p.ccs0 = p.ccs1 = p.ccs2 = 1;
    k_gemm<128, 64, false><<<dim3(8, 48), 256, 0, stream>>>(p, flag);
  }

  // H middle tap += Wp1, and bvec (fused)
  k_prep2<<<1032, 256, 0, stream>>>(Hq, Hk, qproj_w, kproj_w,
                                    convq_b, convk_b, qproj_b, kproj_b, bvec);

  // ---- main Q/K conv3-GEMM: M=8192, N=1024, K=3072 (BK=64) -> QKb ----
  {
    GemmP p{};
    p.A0 = pad;
    p.B0 = Hq; p.B1 = Hk; p.B2 = Hk;
    p.bias0 = bvec; p.bias1 = bvec + 1024; p.bias2 = bvec + 1024;
    p.C0 = p.C1 = p.C2 = QKb;
    p.a_jump = 4096; p.at_jump = 2048;
    p.cj0 = p.cj1 = p.cj2 = 0; p.ct_jump = 0;
    p.b_jump = 0;
    p.rpb = 4096; p.rpt = 2048; p.lda = 1024; p.ldb = 3072;
    p.bsel_by_n = 0; p.bshift = 12; p.K = 3072; p.csel_by_n = 0;
    p.crs0 = p.crs1 = p.crs2 = 1024; p.ccs0 = p.ccs1 = p.ccs2 = 1;
    k_gemm<128, 64, false><<<dim3(8, 64), 256, 0, stream>>>(p, flag);
  }

  // out weights -> dead cvout region (pad now holds pO partials)
  {
    CanonArgs co{};
    co.src[0] = d_in[23]; co.src[1] = d_in[24];
    k_canon<<<513, 256, 0, stream>>>(co, 23, 2, flag, outw_bf);
  }

  // attention: split-kv partials, then combine
  k_attn<<<2048, 256, 0, stream>>>(QKb, VT, tau, dlt, pO, Lp);
  k_comb<<<2048, 256, 0, stream>>>(pO, Lp, attn_out);

  // output projection (BK=64: 48KB LDS, 3 blocks/CU >= grid 2/CU)
  {
    GemmP p{};
    p.A0 = attn_out;
    p.B0 = p.B1 = p.B2 = outw_bf;
    p.bias0 = p.bias1 = p.bias2 = outb_bf;
    p.C0 = p.C1 = p.C2 = (bf16_t*)d_out;
    p.a_jump = 0; p.at_jump = 0;
    p.cj0 = p.cj1 = p.cj2 = 0; p.ct_jump = 0;
    p.b_jump = 0;
    p.rpb = 1 << 30; p.rpt = 1 << 30; p.lda = 1024; p.ldb = 1024;
    p.bsel_by_n = 0; p.bshift = 12; p.K = 1024; p.csel_by_n = 0;
    p.crs0 = p.crs1 = p.crs2 = 1024; p.ccs0 = p.ccs1 = p.ccs2 = 1;
    k_gemm<64, 64, true><<<dim3(16, 32), 256, 0, stream>>>(p, flag);
  }
}

// Round 18
// 369.381 us; speedup vs baseline: 1.0181x; 1.0181x over previous
//
#include <hip/hip_runtime.h>

// DCAttention: B=2, L=2048, D=1024, H=16, DK=64. Runtime dtype detect; compute bf16.
// Proj half-fold: Q = conv3(q_in_pad) @ H^T + bvec, H_k = Wp2@Cw_k (+Wp1 mid tap).
typedef __bf16 bf16_t;
typedef __bf16 bf16x8 __attribute__((ext_vector_type(8)));
typedef __bf16 bf16x4 __attribute__((ext_vector_type(4)));
typedef float f32x4 __attribute__((ext_vector_type(4)));
typedef unsigned uint2v __attribute__((ext_vector_type(2)));

__device__ __forceinline__ void gload_lds16(const bf16_t* g, bf16_t* l) {
  __builtin_amdgcn_global_load_lds(
      (__attribute__((address_space(1))) void*)g,
      (__attribute__((address_space(3))) void*)l, 16, 0, 0);
}

// ---- dtype detection ----
__global__ void k_detect(const unsigned int* __restrict__ xw, int* __restrict__ flag) {
  __shared__ int red[256];
  int c = 0;
  for (int j = 0; j < 16; ++j) {
    unsigned int w = xw[threadIdx.x + (j << 8)];
    unsigned int e = (w >> 7) & 0xFF;
    c += (e >= 100 && e <= 150) ? 1 : 0;
  }
  red[threadIdx.x] = c;
  __syncthreads();
  for (int s = 128; s > 0; s >>= 1) {
    if (threadIdx.x < s) red[threadIdx.x] += red[threadIdx.x + s];
    __syncthreads();
  }
  if (threadIdx.x == 0) flag[0] = (red[0] > 2048) ? 1 : 0;  // 1 = bf16, 0 = f32
}

// ---- canonicalize inputs to bf16 ----
__device__ __constant__ long c_offs[26] = {
    0, 4194304, 4195328, 4196352, 4197376, 4198400, 4199424, 6296576,
    6297600, 8394752, 8395776, 8401920, 8403968, 8436736, 8436752,
    8442896, 8444944, 8477712, 8477728,
    0, 1048576, 2097152, 3145728,
    0, 1048576, 1049600};
struct CanonArgs { const void* src[18]; };

__global__ void k_canon(CanonArgs a, int base, int n, const int* __restrict__ flag,
                        bf16_t* __restrict__ dst) {
  long e0 = ((long)blockIdx.x * 256 + threadIdx.x) * 8;
  if (e0 >= c_offs[base + n]) return;
  int k = 0;
  while (e0 >= c_offs[base + k + 1]) ++k;
  const long rel = e0 - c_offs[base + k];
  if (flag[0]) {
    *(bf16x8*)&dst[e0] = *(const bf16x8*)((const bf16_t*)a.src[k] + rel);
  } else {
    const float* sf = (const float*)a.src[k] + rel;
    f32x4 lo = *(const f32x4*)sf;
    f32x4 hi = *(const f32x4*)(sf + 4);
    bf16x8 o;
    o[0] = (bf16_t)lo[0]; o[1] = (bf16_t)lo[1]; o[2] = (bf16_t)lo[2]; o[3] = (bf16_t)lo[3];
    o[4] = (bf16_t)hi[0]; o[5] = (bf16_t)hi[1]; o[6] = (bf16_t)hi[2]; o[7] = (bf16_t)hi[3];
    *(bf16x8*)&dst[e0] = o;
  }
}

// zero rows 0 and 2049 of each of the 4 pad batches; zero zvec
__global__ void k_zero_pads(bf16_t* __restrict__ pad, bf16_t* __restrict__ zvec) {
  int idx = blockIdx.x * 256 + threadIdx.x;
  if (idx < 1024) zvec[idx] = (bf16_t)0.0f;
  if (idx >= 8192) return;
  int b = idx >> 11;
  int r = (idx >> 10) & 1;
  int c = idx & 1023;
  long row = (long)b * 2050 + (r ? 2049 : 0);
  pad[row * 1024 + c] = (bf16_t)0.0f;
}

// conv weight (O=o, I=i, 3=k) -> ctT[(k*1024+i), o]  (tiled LDS transpose)
__global__ __launch_bounds__(256) void k_ctT(
    const void* __restrict__ wq, const void* __restrict__ wk,
    bf16_t* __restrict__ dq, bf16_t* __restrict__ dk,
    const int* __restrict__ flag) {
  __shared__ bf16_t T[64][72];
  int blk = blockIdx.x;
  const int br = blk >= 768;
  if (br) blk -= 768;
  const void* w = br ? wk : wq;
  bf16_t* dst = br ? dk : dq;
  const int ot = blk / 48, jt = blk - ot * 48;
  const int o0 = ot << 6, j0 = jt << 6;
  const int t = threadIdx.x;
  const int f = flag[0];
#pragma unroll
  for (int it = 0; it < 2; ++it) {
    const int ch = t + (it << 8);
    const int r = ch >> 3, c8 = (ch & 7) << 3;
    const long off = (long)(o0 + r) * 3072 + j0 + c8;
    if (f) {
      *(bf16x8*)&T[r][c8] = *(const bf16x8*)((const bf16_t*)w + off);
    } else {
      const float* sf = (const float*)w + off;
      bf16x8 o8;
#pragma unroll
      for (int e = 0; e < 8; ++e) o8[e] = (bf16_t)sf[e];
      *(bf16x8*)&T[r][c8] = o8;
    }
  }
  __syncthreads();
  const int j = t >> 2, oc0 = (t & 3) << 4;
  const int jj = j0 + j;
  const int drow = (jj % 3) * 1024 + jj / 3;   // tap*1024 + i
  bf16_t* dp = dst + (long)drow * 1024 + o0 + oc0;
#pragma unroll
  for (int s = 0; s < 16; ++s) dp[s] = T[oc0 + s][j];
}

// fused: blocks [0,1024) H middle tap += Wp1; blocks [1024,1032) bvec
__global__ __launch_bounds__(256) void k_prep2(
    bf16_t* __restrict__ Hq, bf16_t* __restrict__ Hk,
    const bf16_t* __restrict__ qp, const bf16_t* __restrict__ kp,
    const bf16_t* __restrict__ cqb, const bf16_t* __restrict__ ckb,
    const bf16_t* __restrict__ qpb, const bf16_t* __restrict__ kpb,
    bf16_t* __restrict__ bvec) {
  if (blockIdx.x < 1024) {
    const long e0 = ((long)blockIdx.x * 256 + threadIdx.x) * 8;
    if (e0 >= 2097152L) return;
    const int br = (int)(e0 >> 20);
    const int rem = (int)(e0 & 1048575);
    const int o = rem >> 10, i = rem & 1023;
    bf16_t* hh = (br ? Hk : Hq) + (long)o * 3072 + 1024 + i;
    const bf16_t* ww = (br ? kp : qp) + (long)o * 2048 + i;
    bf16x8 a = *(const bf16x8*)hh;
    bf16x8 b2 = *(const bf16x8*)ww;
    bf16x8 r;
#pragma unroll
    for (int e = 0; e < 8; ++e) r[e] = (bf16_t)((float)a[e] + (float)b2[e]);
    *(bf16x8*)hh = r;
  } else {
    const int idx = (blockIdx.x - 1024) * 256 + threadIdx.x;
    if (idx >= 2048) return;
    const int br = idx >> 10, o = idx & 1023;
    const bf16_t* wrow = (br ? kp : qp) + (long)o * 2048 + 1024;
    const bf16_t* cb = br ? ckb : cqb;
    float s = 0.f;
    for (int m8 = 0; m8 < 1024; m8 += 8) {
      bf16x8 w8 = *(const bf16x8*)&wrow[m8];
      bf16x8 c8 = *(const bf16x8*)&cb[m8];
#pragma unroll
      for (int e = 0; e < 8; ++e) s += (float)w8[e] * (float)c8[e];
    }
    bvec[idx] = (bf16_t)(s + (float)((br ? kpb : qpb)[o]));
  }
}

// ---- generalized 128xBN GEMM: C = A*B^T + bias, two-level (batch,tap) jumps ----
// LDS tiles XOR-chunk-swizzled (T2); single-barrier counted pipeline; BK templated.
struct GemmP {
  const bf16_t *A0;
  const bf16_t *B0, *B1, *B2;
  const bf16_t *bias0, *bias1, *bias2;
  bf16_t *C0, *C1, *C2;
  long a_jump, at_jump;
  long cj0, cj1, cj2, ct_jump;
  long b_jump;            // if nonzero: Bp = B0 + bidx*b_jump
  int rpb, rpt, lda, ldb, bsel_by_n, bshift, K, csel_by_n;
  int crs0, ccs0, crs1, ccs1, crs2, ccs2;
};

template <int BN, int BK, bool FINAL>
__global__ __launch_bounds__(256) void k_gemm(GemmP p, const int* __restrict__ flagp) {
  __shared__ __align__(16) bf16_t As[2][128 * BK];
  __shared__ __align__(16) bf16_t Bs[2][BN * BK];
  constexpr int CPR = BK / 8;        // 16B chunks per row
  const int tid = threadIdx.x;
  const int gx = gridDim.x;
  int lin = blockIdx.y * gx + blockIdx.x;
  const int nwg = gx * gridDim.y;
  lin = ((lin & 7) * (nwg >> 3)) + (lin >> 3);   // XCD-bijective swizzle (nwg % 8 == 0)
  const int n0 = (lin % gx) * BN;
  const int m0 = (lin / gx) << 7;
  const int batch = m0 / p.rpb;
  const int tap = (m0 - batch * p.rpb) / p.rpt;
  const int bidx = p.bsel_by_n ? (n0 >> 10) : (m0 >> p.bshift);
  const bf16_t* Bp = p.b_jump ? (p.B0 + (long)bidx * p.b_jump)
                              : (bidx == 0 ? p.B0 : (bidx == 1 ? p.B1 : p.B2));
  const bf16_t* biasp = bidx == 0 ? p.bias0 : (bidx == 1 ? p.bias1 : p.bias2);
  const long abase = (long)batch * p.a_jump + (long)tap * p.at_jump;
  const int wid = tid >> 6, lane = tid & 63;
  const int l15 = lane & 15, lg = lane >> 4;
  const int nloc = n0 & 1023;

  constexpr int MI = (BN == 128) ? 4 : 2;
  const int wr = (BN == 128) ? ((wid >> 1) << 6) : (wid << 5);
  const int wc = (BN == 128) ? ((wid & 1) << 6) : 0;
  const int l15sw = (l15 >> 1) & (CPR - 1);

  f32x4 acc[MI][4];
#pragma unroll
  for (int i = 0; i < MI; ++i)
#pragma unroll
    for (int j = 0; j < 4; ++j) acc[i][j] = (f32x4){0.f, 0.f, 0.f, 0.f};

  auto stage = [&](int bufi, int k) {
#pragma unroll
    for (int it = 0; it < (128 * CPR) / 256; ++it) {   // A tile chunks
      const int c = it * 256 + tid;
      const int row = c / CPR, kc = c % CPR;
      const int kg = k + ((kc ^ ((row >> 1) & (CPR - 1))) << 3);
      gload_lds16(p.A0 + abase + (long)(m0 + row) * p.lda + kg, &As[bufi][c << 3]);
    }
#pragma unroll
    for (int it = 0; it < (BN * CPR) / 256; ++it) {    // B tile chunks
      const int c = it * 256 + tid;
      const int row = c / CPR, kc = c % CPR;
      const int kg = k + ((kc ^ ((row >> 1) & (CPR - 1))) << 3);
      gload_lds16(Bp + (long)(nloc + row) * p.ldb + kg, &Bs[bufi][c << 3]);
    }
  };

  const int nk = p.K / BK;
  int buf = 0;
  stage(0, 0);
  asm volatile("s_waitcnt vmcnt(0)" ::: "memory");
  __builtin_amdgcn_s_barrier();
  __builtin_amdgcn_sched_barrier(0);
  for (int kt = 0; kt < nk; ++kt) {
    if (kt + 1 < nk) stage(buf ^ 1, (kt + 1) * BK);
#pragma unroll
    for (int kh = 0; kh < BK / 32; ++kh) {
      bf16x8 af[MI], bfr[4];
      const int csw = (((kh << 2) | lg) ^ l15sw) << 3;
#pragma unroll
      for (int i = 0; i < MI; ++i)
        af[i] = *(const bf16x8*)&As[buf][(wr + (i << 4) + l15) * BK + csw];
#pragma unroll
      for (int j = 0; j < 4; ++j)
        bfr[j] = *(const bf16x8*)&Bs[buf][(wc + (j << 4) + l15) * BK + csw];
#pragma unroll
      for (int i = 0; i < MI; ++i)
#pragma unroll
        for (int j = 0; j < 4; ++j)
          acc[i][j] = __builtin_amdgcn_mfma_f32_16x16x32_bf16(af[i], bfr[j], acc[i][j], 0, 0, 0);
    }
    if (kt + 1 < nk) asm volatile("s_waitcnt vmcnt(0)" ::: "memory");
    __builtin_amdgcn_s_barrier();
    __builtin_amdgcn_sched_barrier(0);
    buf ^= 1;
  }

  const int cp = p.csel_by_n ? (n0 >> 10) : (m0 >> p.bshift);
  bf16_t* Cb = cp == 0 ? p.C0 : (cp == 1 ? p.C1 : p.C2);
  const int crs = cp == 0 ? p.crs0 : (cp == 1 ? p.crs1 : p.crs2);
  const int ccs = cp == 0 ? p.ccs0 : (cp == 1 ? p.ccs1 : p.ccs2);
  const long cj = cp == 0 ? p.cj0 : (cp == 1 ? p.cj1 : p.cj2);
  const bool f32out = FINAL && (flagp[0] == 0);
  const long cbase = (long)batch * cj + (long)tap * p.ct_jump;
#pragma unroll
  for (int i = 0; i < MI; ++i) {
    const int row = m0 + wr + (i << 4) + (lg << 2);
#pragma unroll
    for (int j = 0; j < 4; ++j) {
      const int col = nloc + wc + (j << 4) + l15;
      const float bv = (float)biasp[col];
#pragma unroll
      for (int r = 0; r < 4; ++r) {
        const float val = acc[i][j][r] + bv;
        const long ci = cbase + (long)(row + r) * crs + (long)col * ccs;
        if (FINAL && f32out) ((float*)Cb)[ci] = val;
        else Cb[ci] = (bf16_t)val;
      }
    }
  }
}

// tau/delta: depthwise conv3 -> gelu(erf) -> pointwise (2D->H) -> sigmoid.
// dlt is pre-multiplied by log2(e) for the exp2-domain softmax.
__global__ __launch_bounds__(256) void k_taudelta(
    const bf16_t* __restrict__ x,
    const bf16_t* __restrict__ t1w, const bf16_t* __restrict__ t1b,
    const bf16_t* __restrict__ t2w, const bf16_t* __restrict__ t2b,
    const bf16_t* __restrict__ d1w, const bf16_t* __restrict__ d1b,
    const bf16_t* __restrict__ d2w, const bf16_t* __restrict__ d2b,
    float* __restrict__ tau, float* __restrict__ dlt)
{
  const int bt = blockIdx.x;
  const int t = bt & 2047;
  const int b = bt >> 11;
  const int tid = threadIdx.x;
  const bf16_t* xr = x + ((long)bt << 10);

  float acc[32];
#pragma unroll
  for (int i = 0; i < 32; ++i) acc[i] = 0.f;

  for (int j = 0; j < 8; ++j) {
    const int c = tid + (j << 8);
    const int src = c >> 1;
    const float x0 = (float)xr[src];
    const float xm = (t > 0) ? (float)xr[src - 1024] : 0.f;
    const float xp = (t < 2047) ? (float)xr[src + 1024] : 0.f;
    float st = (float)t1w[3 * c] * xm + (float)t1w[3 * c + 1] * x0 +
               (float)t1w[3 * c + 2] * xp + (float)t1b[c];
    float sd = (float)d1w[3 * c] * xm + (float)d1w[3 * c + 1] * x0 +
               (float)d1w[3 * c + 2] * xp + (float)d1b[c];
    const float gt = 0.5f * st * (1.f + erff(st * 0.70710678118f));
    const float gd = 0.5f * sd * (1.f + erff(sd * 0.70710678118f));
#pragma unroll
    for (int h = 0; h < 16; ++h) {
      acc[h]      += (float)t2w[(h << 11) + c] * gt;
      acc[16 + h] += (float)d2w[(h << 11) + c] * gd;
    }
  }

  __shared__ float red[256][33];
  __shared__ float red2[8][32];
#pragma unroll
  for (int i = 0; i < 32; ++i) red[tid][i] = acc[i];
  __syncthreads();
  const int i = tid & 31, g = tid >> 5;
  float p = 0.f;
#pragma unroll
  for (int k2 = 0; k2 < 32; ++k2) p += red[(g << 5) + k2][i];
  __syncthreads();
  red2[g][i] = p;
  __syncthreads();
  if (tid < 32) {
    float s = 0.f;
#pragma unroll
    for (int g2 = 0; g2 < 8; ++g2) s += red2[g2][tid];
    const int h = tid & 15;
    if (tid < 16) {
      s += (float)t2b[h];
      tau[((long)((b << 4) + h) << 11) + t] = 1.f / (1.f + __expf(-s));
    } else {
      s += (float)d2b[h];
      dlt[((long)((b << 4) + h) << 11) + t] =
          1.4426950408889634f / (1.f + __expf(-s));
    }
  }
}

__device__ __forceinline__ unsigned pk2(float a, float b) {
  union { bf16_t h[2]; unsigned u; } z;
  z.h[0] = (bf16_t)a; z.h[1] = (bf16_t)b;
  return z.u;
}

// Flash attention v7 (best measured): exp2-domain no-max softmax, ones-MFMA
// row sum, double-buffered K/V LDS (40KB, 4 blocks/CU), single-barrier pipeline.
__global__ __launch_bounds__(256) void k_attn(
    const bf16_t* __restrict__ QKb, const bf16_t* __restrict__ VT,
    const float* __restrict__ tau, const float* __restrict__ dlt,
    bf16_t* __restrict__ O)
{
  const int lin = blockIdx.x;
  const int wg = ((lin & 7) << 7) + (lin >> 3);   // 1024 blocks, XCD-chunked
  const int bh = wg >> 5, qt = wg & 31;
  const int tid = threadIdx.x;
  const int lane = tid & 63;
  const int wid = tid >> 6;
  const int l15 = lane & 15, lg = lane >> 4;
  const int b = bh >> 4, h = bh & 15;
  const int qbase = (qt << 6) + (wid << 4);

  const bf16_t* Qp = QKb + ((long)b << 21) + (h << 6);
  const bf16_t* Kp = QKb + 4194304 + ((long)b << 21) + (h << 6);
  const bf16_t* Vp = VT + ((long)bh << 17);

  __shared__ __align__(16) bf16_t Ks[2][4096];   // 64 kv x 64 d
  __shared__ __align__(16) bf16_t Vs[2][4096];   // 64 d  x 64 kv
  __shared__ unsigned Plds[4][16][32];

  bf16x8 qf[2];
#pragma unroll
  for (int kd = 0; kd < 2; ++kd)
    qf[kd] = *(const bf16x8*)&Qp[((long)(qbase + l15) << 10) + (kd << 5) + (lg << 3)];
  const float tq = tau[((long)bh << 11) + qbase + l15] * (0.125f * 1.4426950408889634f);

  bf16x8 onesf;
#pragma unroll
  for (int e = 0; e < 8; ++e) onesf[e] = (bf16_t)1.0f;

  f32x4 accO[4];
#pragma unroll
  for (int d = 0; d < 4; ++d) accO[d] = (f32x4){0.f, 0.f, 0.f, 0.f};
  f32x4 accL = (f32x4){0.f, 0.f, 0.f, 0.f};

  const int xr = (l15 & 7) << 2;
  const int c0 = ((lg ^ (l15 & 7)) << 3);
  const int c1 = (((4 | lg) ^ (l15 & 7)) << 3);
  const int rowb = l15 << 6;
  const int sK_r0 = tid >> 3, sK_c0 = ((tid & 7) ^ (sK_r0 & 7)) << 3;
  const int sK_r1 = (tid + 256) >> 3, sK_c1 = (((tid + 256) & 7) ^ (sK_r1 & 7)) << 3;
  const bf16_t* kb0 = Kp + ((long)sK_r0 << 10) + sK_c0;
  const bf16_t* kb1 = Kp + ((long)sK_r1 << 10) + sK_c1;
  const bf16_t* vb0 = Vp + ((long)sK_r0 << 11) + sK_c0;
  const bf16_t* vb1 = Vp + ((long)sK_r1 << 11) + sK_c1;
  bf16_t* ldK0[2] = {&Ks[0][tid << 3], &Ks[1][tid << 3]};
  bf16_t* ldK1[2] = {&Ks[0][(tid + 256) << 3], &Ks[1][(tid + 256) << 3]};
  bf16_t* ldV0[2] = {&Vs[0][tid << 3], &Vs[1][tid << 3]};
  bf16_t* ldV1[2] = {&Vs[0][(tid + 256) << 3], &Vs[1][(tid + 256) << 3]};
  const float* dlp = dlt + ((long)bh << 11) + (lg << 2);

  auto stageKV = [&](int bufi, int kk) {
    gload_lds16(kb0 + ((long)kk << 10), ldK0[bufi]);
    gload_lds16(kb1 + ((long)kk << 10), ldK1[bufi]);
    gload_lds16(vb0 + kk, ldV0[bufi]);
    gload_lds16(vb1 + kk, ldV1[bufi]);
  };

  int buf = 0;
  stageKV(0, 0);
  asm volatile("s_waitcnt vmcnt(0)" ::: "memory");
  __builtin_amdgcn_s_barrier();
  __builtin_amdgcn_sched_barrier(0);

  for (int kk = 0; kk < 2048; kk += 64) {
    if (kk + 64 < 2048) stageKV(buf ^ 1, kk + 64);

    f32x4 st[4];
    __builtin_amdgcn_s_setprio(1);
#pragma unroll
    for (int kb = 0; kb < 4; ++kb) {
      const int rk = (kb << 10) + rowb;
      f32x4 z = (f32x4){0.f, 0.f, 0.f, 0.f};
      z = __builtin_amdgcn_mfma_f32_16x16x32_bf16(
          *(const bf16x8*)&Ks[buf][rk + c0], qf[0], z, 0, 0, 0);
      z = __builtin_amdgcn_mfma_f32_16x16x32_bf16(
          *(const bf16x8*)&Ks[buf][rk + c1], qf[1], z, 0, 0, 0);
      st[kb] = z;
    }
    __builtin_amdgcn_s_setprio(0);

#pragma unroll
    for (int kb = 0; kb < 4; ++kb) {
      const f32x4 dl = *(const f32x4*)(dlp + kk + (kb << 4));
      const float p0 = exp2f(fmaf(st[kb][0], tq, dl[0]));
      const float p1 = exp2f(fmaf(st[kb][1], tq, dl[1]));
      const float p2 = exp2f(fmaf(st[kb][2], tq, dl[2]));
      const float p3 = exp2f(fmaf(st[kb][3], tq, dl[3]));
      uint2v pp;
      pp[0] = pk2(p0, p1);
      pp[1] = pk2(p2, p3);
      *(uint2v*)&Plds[wid][l15][((kb << 3) + (lg << 1)) ^ xr] = pp;
    }
    asm volatile("s_waitcnt lgkmcnt(0)" ::: "memory");
    __builtin_amdgcn_sched_barrier(0);
    const bf16x8 pf0 = *(const bf16x8*)&Plds[wid][l15][(lg << 2) ^ xr];
    const bf16x8 pf1 = *(const bf16x8*)&Plds[wid][l15][(16 | (lg << 2)) ^ xr];
    asm volatile("s_waitcnt lgkmcnt(0)" ::: "memory");
    __builtin_amdgcn_sched_barrier(0);

    __builtin_amdgcn_s_setprio(1);
#pragma unroll
    for (int d = 0; d < 4; ++d) {
      const int rv = (d << 10) + rowb;
      accO[d] = __builtin_amdgcn_mfma_f32_16x16x32_bf16(
          *(const bf16x8*)&Vs[buf][rv + c0], pf0, accO[d], 0, 0, 0);
      accO[d] = __builtin_amdgcn_mfma_f32_16x16x32_bf16(
          *(const bf16x8*)&Vs[buf][rv + c1], pf1, accO[d], 0, 0, 0);
    }
    accL = __builtin_amdgcn_mfma_f32_16x16x32_bf16(onesf, pf0, accL, 0, 0, 0);
    accL = __builtin_amdgcn_mfma_f32_16x16x32_bf16(onesf, pf1, accL, 0, 0, 0);
    __builtin_amdgcn_s_setprio(0);

    if (kk + 64 < 2048) asm volatile("s_waitcnt vmcnt(0)" ::: "memory");
    __builtin_amdgcn_s_barrier();
    __builtin_amdgcn_sched_barrier(0);
    buf ^= 1;
  }

  bf16_t* Ob = O + ((long)b << 21) + (h << 6);
  const float inv = 1.f / accL[0];
#pragma unroll
  for (int d = 0; d < 4; ++d) {
    bf16x4 ov;
#pragma unroll
    for (int r = 0; r < 4; ++r) ov[r] = (bf16_t)(accO[d][r] * inv);
    *(bf16x4*)&Ob[((long)(qbase + l15) << 10) + (d << 4) + (lg << 2)] = ov;
  }
}

extern "C" void kernel_launch(void* const* d_in, const int* in_sizes, int n_in,
                              void* d_out, int out_size, void* d_ws, size_t ws_size,
                              hipStream_t stream) {
  char* w = (char*)d_ws;
  int* flag     = (int*)w;                      // 16 B
  bf16_t* canon = (bf16_t*)(w + 16);            // 16,955,456 B
  bf16_t* pad   = (bf16_t*)(w + 16955472);      // 16,793,600 B (4 batches x 2050 x 1024)
  bf16_t* swq   = (bf16_t*)(w + 33749072);      // 6,291,456 B (Wq/Wk/Wv; later tau/dlt/bvec/zvec)
  bf16_t* cvout = (bf16_t*)(w + 40040528);      // 8,388,608 B (H_q)
  bf16_t* QKb   = (bf16_t*)(w + 48429136);      // 16,777,216 B (ctT -> Q|K)
  bf16_t* VT    = (bf16_t*)(w + 65206352);      // 8,388,608 B

  // canon element offsets
  bf16_t* xc      = canon;
  bf16_t* Wq_b    = canon + 4194304;
  bf16_t* Wk_b    = canon + 4195328;
  bf16_t* Wv_b    = canon + 4196352;
  bf16_t* convq_b = canon + 4197376;
  bf16_t* convk_b = canon + 4198400;
  bf16_t* qproj_w = canon + 4199424;
  bf16_t* qproj_b = canon + 6296576;
  bf16_t* kproj_w = canon + 6297600;
  bf16_t* kproj_b = canon + 8394752;
  bf16_t* tau1_w  = canon + 8395776;
  bf16_t* tau1_b  = canon + 8401920;
  bf16_t* tau2_w  = canon + 8403968;
  bf16_t* tau2_b  = canon + 8436736;
  bf16_t* del1_w  = canon + 8436752;
  bf16_t* del1_b  = canon + 8442896;
  bf16_t* del2_w  = canon + 8444944;
  bf16_t* del2_b  = canon + 8477712;

  bf16_t* pad_q = pad;
  bf16_t* Wq_w = swq, *Wk_w = swq + 1048576, *Wv_w = swq + 2097152;
  float* tau = (float*)swq;                     // after QKV GEMM, swq is dead
  float* dlt = (float*)((char*)swq + 262144);
  bf16_t* bvec = (bf16_t*)((char*)swq + 524288);
  bf16_t* zvec = (bf16_t*)((char*)swq + 528384);
  bf16_t* ctT_q = QKb;                          // 3072x1024 per branch
  bf16_t* ctT_k = QKb + 3145728;
  bf16_t* Hq = cvout;                           // [o][tap*1024+i]
  bf16_t* Hk = xc;                              // x dead after QKV + taudelta
  const long hk_delta = (long)(Hk - Hq);
  bf16_t* outw_bf = pad;                        // pad dead after main GEMM
  bf16_t* outb_bf = pad + 1048576;
  bf16_t* attn_out = xc;                        // Hk dead after main GEMM

  k_detect<<<1, 256, 0, stream>>>((const unsigned int*)d_in[0], flag);

  CanonArgs ca{};
  {
    const int idxA[18] = {0, 2, 4, 6, 8, 10, 11, 12, 13, 14,
                          15, 16, 17, 18, 19, 20, 21, 22};
    for (int i = 0; i < 18; ++i) ca.src[i] = d_in[idxA[i]];
    k_canon<<<4140, 256, 0, stream>>>(ca, 0, 18, flag, canon);
  }
  {
    CanonArgs cw{};
    cw.src[0] = d_in[1]; cw.src[1] = d_in[3]; cw.src[2] = d_in[5];
    k_canon<<<1536, 256, 0, stream>>>(cw, 19, 3, flag, swq);
  }
  k_zero_pads<<<32, 256, 0, stream>>>(pad, zvec);

  // ---- fused QKV in-projection: M=4096, N=3072, K=1024 (BK=32, 3 blocks/CU) ----
  {
    GemmP p{};
    p.A0 = xc;
    p.B0 = Wq_w; p.B1 = Wk_w; p.B2 = Wv_w;
    p.bias0 = Wq_b; p.bias1 = Wk_b; p.bias2 = Wv_b;
    p.C0 = pad_q + 1024; p.C1 = pad_q + 4198400 + 1024; p.C2 = VT;
    p.a_jump = 0; p.at_jump = 0;
    p.cj0 = 2048; p.cj1 = 2048; p.cj2 = 2095104; p.ct_jump = 0;
    p.b_jump = 0;
    p.rpb = 2048; p.rpt = 1 << 30; p.lda = 1024; p.ldb = 1024;
    p.bsel_by_n = 1; p.bshift = 12; p.K = 1024; p.csel_by_n = 1;
    p.crs0 = 1024; p.ccs0 = 1; p.crs1 = 1024; p.ccs1 = 1; p.crs2 = 1; p.ccs2 = 2048;
    k_gemm<128, 32, false><<<dim3(24, 32), 256, 0, stream>>>(p, flag);
  }

  // tau/delta (into dead swq region)
  k_taudelta<<<4096, 256, 0, stream>>>(xc, tau1_w, tau1_b, tau2_w, tau2_b,
                                       del1_w, del1_b, del2_w, del2_b, tau, dlt);

  // conv weight transposes ctT[(k,i), o]
  k_ctT<<<1536, 256, 0, stream>>>(d_in[7], d_in[9], ctT_q, ctT_k, flag);

  // ---- H = Wp2 @ Cw: M=6144 ((br,tap,o)), N=1024 (i), K=1024 (BK=64) ----
  {
    GemmP p{};
    p.A0 = qproj_w + 1024;
    p.B0 = ctT_q; p.B1 = ctT_q; p.B2 = ctT_q;
    p.bias0 = p.bias1 = p.bias2 = zvec;
    p.C0 = p.C1 = p.C2 = Hq;
    p.a_jump = (long)(kproj_w - qproj_w) - 3072L * 2048;   // -4193280
    p.at_jump = -2097152;
    p.cj0 = p.cj1 = p.cj2 = hk_delta - 9437184;
    p.ct_jump = -3144704;
    p.b_jump = 1048576;
    p.rpb = 3072; p.rpt = 1024; p.lda = 2048; p.ldb = 1024;
    p.bsel_by_n = 0; p.bshift = 10; p.K = 1024; p.csel_by_n = 0;
    p.crs0 = p.crs1 = p.crs2 = 3072; p.ccs0 = p.ccs1 = p.ccs2 = 1;
    k_gemm<128, 64, false><<<dim3(8, 48), 256, 0, stream>>>(p, flag);
  }

  // H middle tap += Wp1, and bvec (fused)
  k_prep2<<<1032, 256, 0, stream>>>(Hq, Hk, qproj_w, kproj_w,
                                    convq_b, convk_b, qproj_b, kproj_b, bvec);

  // ---- main Q/K conv3-GEMM: M=8192, N=1024, K=3072 (BK=64) -> QKb ----
  {
    GemmP p{};
    p.A0 = pad;
    p.B0 = Hq; p.B1 = Hk; p.B2 = Hk;
    p.bias0 = bvec; p.bias1 = bvec + 1024; p.bias2 = bvec + 1024;
    p.C0 = p.C1 = p.C2 = QKb;
    p.a_jump = 4096; p.at_jump = 2048;
    p.cj0 = p.cj1 = p.cj2 = 0; p.ct_jump = 0;
    p.b_jump = 0;
    p.rpb = 4096; p.rpt = 2048; p.lda = 1024; p.ldb = 3072;
    p.bsel_by_n = 0; p.bshift = 12; p.K = 3072; p.csel_by_n = 0;
    p.crs0 = p.crs1 = p.crs2 = 1024; p.ccs0 = p.ccs1 = p.ccs2 = 1;
    k_gemm<128, 64, false><<<dim3(8, 64), 256, 0, stream>>>(p, flag);
  }

  // out weights -> dead pad region
  {
    CanonArgs co{};
    co.src[0] = d_in[23]; co.src[1] = d_in[24];
    k_canon<<<513, 256, 0, stream>>>(co, 23, 2, flag, outw_bf);
  }

  // attention
  k_attn<<<1024, 256, 0, stream>>>(QKb, VT, tau, dlt, attn_out);

  // output projection (BK=64: 48KB LDS, 3 blocks/CU >= grid 2/CU)
  {
    GemmP p{};
    p.A0 = attn_out;
    p.B0 = p.B1 = p.B2 = outw_bf;
    p.bias0 = p.bias1 = p.bias2 = outb_bf;
    p.C0 = p.C1 = p.C2 = (bf16_t*)d_out;
    p.a_jump = 0; p.at_jump = 0;
    p.cj0 = p.cj1 = p.cj2 = 0; p.ct_jump = 0;
    p.b_jump = 0;
    p.rpb = 1 << 30; p.rpt = 1 << 30; p.lda = 1024; p.ldb = 1024;
    p.bsel_by_n = 0; p.bshift = 12; p.K = 1024; p.csel_by_n = 0;
    p.crs0 = p.crs1 = p.crs2 = 1024; p.ccs0 = p.ccs1 = p.ccs2 = 1;
    k_gemm<64, 64, true><<<dim3(16, 32), 256, 0, stream>>>(p, flag);
  }
}